// Round 1
// baseline (3691.251 us; speedup 1.0000x reference)
//
#include <hip/hip_runtime.h>
#include <hip/hip_bf16.h>

#define T_SEQ 4096
#define D_MODEL 768
#define N_HEADS 12
#define HEAD_DIM 64
#define FF_DIM 3072

// ---------------------------------------------------------------------------
// LayerNorm: one 256-thread block per row (D=768 -> 3 elements/thread)
// ---------------------------------------------------------------------------
__global__ __launch_bounds__(256) void ln_kernel(const float* __restrict__ x,
                                                 const float* __restrict__ g,
                                                 const float* __restrict__ b,
                                                 float* __restrict__ o) {
    const int row = blockIdx.x;
    const float* xr = x + (size_t)row * D_MODEL;
    float* orow = o + (size_t)row * D_MODEL;
    const int tid = threadIdx.x;

    float v0 = xr[tid];
    float v1 = xr[tid + 256];
    float v2 = xr[tid + 512];
    float sum = v0 + v1 + v2;

    __shared__ float red[4];
    __shared__ float mv[2];
    const int lane = tid & 63, wv = tid >> 6;

    #pragma unroll
    for (int off = 32; off > 0; off >>= 1) sum += __shfl_down(sum, off, 64);
    if (lane == 0) red[wv] = sum;
    __syncthreads();
    if (tid == 0) mv[0] = (red[0] + red[1] + red[2] + red[3]) * (1.0f / D_MODEL);
    __syncthreads();
    const float mean = mv[0];

    float d0 = v0 - mean, d1 = v1 - mean, d2 = v2 - mean;
    float sq = d0 * d0 + d1 * d1 + d2 * d2;
    #pragma unroll
    for (int off = 32; off > 0; off >>= 1) sq += __shfl_down(sq, off, 64);
    if (lane == 0) red[wv] = sq;
    __syncthreads();
    if (tid == 0) mv[1] = (red[0] + red[1] + red[2] + red[3]) * (1.0f / D_MODEL);
    __syncthreads();
    const float rs = rsqrtf(mv[1] + 1e-5f);

    orow[tid]       = g[tid]       * d0 * rs + b[tid];
    orow[tid + 256] = g[tid + 256] * d1 * rs + b[tid + 256];
    orow[tid + 512] = g[tid + 512] * d2 * rs + b[tid + 512];
}

// ---------------------------------------------------------------------------
// fp32 tiled GEMM: C[M,N] = A[M,K] @ B[K,N] (+ bias[N]) (+ res[M,N])
// BM=BN=64, BK=16, 256 threads, 4x4 micro-tile per thread.
// M,N multiples of 64; K multiple of 16.
// ---------------------------------------------------------------------------
#define GBM 64
#define GBN 64
#define GBK 16
#define GPAD 4

__global__ __launch_bounds__(256) void gemm_kernel(const float* __restrict__ A,
                                                   const float* __restrict__ B,
                                                   const float* __restrict__ bias,
                                                   const float* __restrict__ res,
                                                   float* __restrict__ C,
                                                   int M, int N, int K) {
    __shared__ float As[GBK][GBM + GPAD];
    __shared__ float Bs[GBK][GBN + GPAD];

    const int tid = threadIdx.x;
    const int bn = blockIdx.x * GBN;
    const int bm = blockIdx.y * GBM;
    const int tx = tid & 15;      // 0..15 -> col group
    const int ty = tid >> 4;      // 0..15 -> row group

    const int ar = tid >> 2;            // 0..63  A tile row
    const int ac = (tid & 3) * 4;       // 0,4,8,12  A tile k-col
    const int br = tid >> 4;            // 0..15  B tile k-row
    const int bc = (tid & 15) * 4;      // 0..60  B tile col

    float acc[4][4] = {};

    for (int k0 = 0; k0 < K; k0 += GBK) {
        float4 av = *(const float4*)(A + (size_t)(bm + ar) * K + k0 + ac);
        As[ac + 0][ar] = av.x;
        As[ac + 1][ar] = av.y;
        As[ac + 2][ar] = av.z;
        As[ac + 3][ar] = av.w;
        float4 bv = *(const float4*)(B + (size_t)(k0 + br) * N + bn + bc);
        *(float4*)(&Bs[br][bc]) = bv;
        __syncthreads();

        #pragma unroll
        for (int kk = 0; kk < GBK; ++kk) {
            float4 a = *(const float4*)(&As[kk][ty * 4]);
            float4 b = *(const float4*)(&Bs[kk][tx * 4]);
            acc[0][0] += a.x * b.x; acc[0][1] += a.x * b.y; acc[0][2] += a.x * b.z; acc[0][3] += a.x * b.w;
            acc[1][0] += a.y * b.x; acc[1][1] += a.y * b.y; acc[1][2] += a.y * b.z; acc[1][3] += a.y * b.w;
            acc[2][0] += a.z * b.x; acc[2][1] += a.z * b.y; acc[2][2] += a.z * b.z; acc[2][3] += a.z * b.w;
            acc[3][0] += a.w * b.x; acc[3][1] += a.w * b.y; acc[3][2] += a.w * b.z; acc[3][3] += a.w * b.w;
        }
        __syncthreads();
    }

    const int n0 = bn + tx * 4;
    float4 bias4 = make_float4(0.f, 0.f, 0.f, 0.f);
    if (bias) bias4 = *(const float4*)(bias + n0);

    #pragma unroll
    for (int i = 0; i < 4; ++i) {
        const int m = bm + ty * 4 + i;
        float4 out;
        out.x = acc[i][0] + bias4.x;
        out.y = acc[i][1] + bias4.y;
        out.z = acc[i][2] + bias4.z;
        out.w = acc[i][3] + bias4.w;
        if (res) {
            float4 r = *(const float4*)(res + (size_t)m * N + n0);
            out.x += r.x; out.y += r.y; out.z += r.z; out.w += r.w;
        }
        *(float4*)(C + (size_t)m * N + n0) = out;
    }
}

// ---------------------------------------------------------------------------
// Flash-style causal attention, fp32. One block per (q-tile of 32, head).
// Q/K/V/O in [T, D] layout, head slice at column h*HEAD_DIM.
// ---------------------------------------------------------------------------
#define AQ 32
#define AK 64

__global__ __launch_bounds__(256) void attn_kernel(const float* __restrict__ Q,
                                                   const float* __restrict__ K,
                                                   const float* __restrict__ V,
                                                   float* __restrict__ O) {
    const int qt = blockIdx.x;
    const int h = blockIdx.y;
    const int q0 = qt * AQ;
    const int tid = threadIdx.x;

    __shared__ float Qs[AQ][HEAD_DIM];        // broadcast-by-row reads
    __shared__ float Ks[AK][HEAD_DIM + 1];    // lane-per-row reads -> pad
    __shared__ float Vs[AK][HEAD_DIM];        // lane-per-col reads
    __shared__ float Ssc[AQ][AK + 1];         // pad for 32-row softmax scan
    __shared__ float accs[AQ][HEAD_DIM];
    __shared__ float mrow[AQ], lrow[AQ], arow[AQ];

    // load Q tile (32 rows x 64 cols), float4
    for (int idx = tid; idx < AQ * (HEAD_DIM / 4); idx += 256) {
        const int qi = idx >> 4;
        const int c = (idx & 15) * 4;
        float4 v = *(const float4*)(Q + (size_t)(q0 + qi) * D_MODEL + h * HEAD_DIM + c);
        *(float4*)(&Qs[qi][c]) = v;
    }
    for (int idx = tid; idx < AQ * HEAD_DIM; idx += 256)
        ((float*)accs)[idx] = 0.0f;
    if (tid < AQ) { mrow[tid] = -1e30f; lrow[tid] = 0.0f; }
    __syncthreads();

    const float scale = 0.125f;  // 1/sqrt(64)
    const int ktiles = (q0 + AQ - 1) / AK + 1;

    for (int kt = 0; kt < ktiles; ++kt) {
        const int k0 = kt * AK;
        // load K/V tiles
        for (int idx = tid; idx < AK * (HEAD_DIM / 4); idx += 256) {
            const int kj = idx >> 4;
            const int c = (idx & 15) * 4;
            float4 kv = *(const float4*)(K + (size_t)(k0 + kj) * D_MODEL + h * HEAD_DIM + c);
            Ks[kj][c + 0] = kv.x; Ks[kj][c + 1] = kv.y; Ks[kj][c + 2] = kv.z; Ks[kj][c + 3] = kv.w;
            float4 vv = *(const float4*)(V + (size_t)(k0 + kj) * D_MODEL + h * HEAD_DIM + c);
            *(float4*)(&Vs[kj][c]) = vv;
        }
        __syncthreads();

        // scores: 32x64 pairs, 8 per thread; lanes of a wave share qi
        #pragma unroll
        for (int p = 0; p < 8; ++p) {
            const int idx = tid + p * 256;
            const int qi = idx >> 6;
            const int kj = idx & 63;
            float sc;
            if (k0 + kj > q0 + qi) {
                sc = -1e30f;
            } else {
                float s = 0.0f;
                #pragma unroll
                for (int d = 0; d < HEAD_DIM; ++d) s += Qs[qi][d] * Ks[kj][d];
                sc = s * scale;
            }
            Ssc[qi][kj] = sc;
        }
        __syncthreads();

        // online softmax per row
        if (tid < AQ) {
            const float mold = mrow[tid];
            float mx = mold;
            for (int j = 0; j < AK; ++j) mx = fmaxf(mx, Ssc[tid][j]);
            float s = 0.0f;
            for (int j = 0; j < AK; ++j) {
                float p = __expf(Ssc[tid][j] - mx);
                Ssc[tid][j] = p;
                s += p;
            }
            const float alpha = __expf(mold - mx);
            mrow[tid] = mx;
            lrow[tid] = lrow[tid] * alpha + s;
            arow[tid] = alpha;
        }
        __syncthreads();

        // acc update: 32x64 (qi, d) pairs, 8 per thread
        #pragma unroll
        for (int p = 0; p < 8; ++p) {
            const int idx = tid + p * 256;
            const int qi = idx >> 6;
            const int d = idx & 63;
            float a = accs[qi][d] * arow[qi];
            #pragma unroll 16
            for (int j = 0; j < AK; ++j) a += Ssc[qi][j] * Vs[j][d];
            accs[qi][d] = a;
        }
        __syncthreads();
    }

    // write out: ctx[q][h*64+d] = acc / l
    #pragma unroll
    for (int p = 0; p < 8; ++p) {
        const int idx = tid + p * 256;
        const int qi = idx >> 6;
        const int d = idx & 63;
        O[(size_t)(q0 + qi) * D_MODEL + h * HEAD_DIM + d] = accs[qi][d] / lrow[qi];
    }
}

// ---------------------------------------------------------------------------
// SwiGLU elementwise: o = silu(a) * g   (in-place safe: o may alias a)
// ---------------------------------------------------------------------------
__global__ __launch_bounds__(256) void swiglu_kernel(const float* __restrict__ a,
                                                     const float* __restrict__ g,
                                                     float* __restrict__ o,
                                                     int n4) {
    const int i = blockIdx.x * 256 + threadIdx.x;
    if (i < n4) {
        float4 av = ((const float4*)a)[i];
        float4 gv = ((const float4*)g)[i];
        float4 ov;
        ov.x = av.x / (1.0f + __expf(-av.x)) * gv.x;
        ov.y = av.y / (1.0f + __expf(-av.y)) * gv.y;
        ov.z = av.z / (1.0f + __expf(-av.z)) * gv.z;
        ov.w = av.w / (1.0f + __expf(-av.w)) * gv.w;
        ((float4*)o)[i] = ov;
    }
}

// ---------------------------------------------------------------------------
// launch
// ---------------------------------------------------------------------------
extern "C" void kernel_launch(void* const* d_in, const int* in_sizes, int n_in,
                              void* d_out, int out_size, void* d_ws, size_t ws_size,
                              hipStream_t stream) {
    const float* x  = (const float*)d_in[0];
    const float* Wq = (const float*)d_in[1];
    const float* Wk = (const float*)d_in[2];
    const float* Wv = (const float*)d_in[3];
    const float* Wo = (const float*)d_in[4];
    const float* bo = (const float*)d_in[5];
    const float* w1 = (const float*)d_in[6];
    const float* b1 = (const float*)d_in[7];
    const float* w2 = (const float*)d_in[8];
    const float* b2 = (const float*)d_in[9];
    const float* w3 = (const float*)d_in[10];
    const float* b3 = (const float*)d_in[11];
    const float* g1 = (const float*)d_in[12];
    const float* s1 = (const float*)d_in[13];
    const float* g2 = (const float*)d_in[14];
    const float* s2 = (const float*)d_in[15];
    float* out = (float*)d_out;

    const size_t TD = (size_t)T_SEQ * D_MODEL;     // 3.1M floats
    const size_t TF = (size_t)T_SEQ * FF_DIM;      // 12.6M floats

    float* ws = (float*)d_ws;
    float* h    = ws;            // TD   (reused as ctx after QKV)
    float* Qb   = h    + TD;     // TD
    float* Kb   = Qb   + TD;     // TD
    float* Vb   = Kb   + TD;     // TD
    float* x2   = Vb   + TD;     // TD
    float* h2   = x2   + TD;     // TD
    float* abuf = h2   + TD;     // TF  (reused as u after swiglu)
    float* gbuf = abuf + TF;     // TF

    // 1. h = LN(x; g1, s1)
    ln_kernel<<<T_SEQ, 256, 0, stream>>>(x, g1, s1, h);

    // 2-4. Q/K/V = h @ W{q,k,v}
    dim3 gsq(D_MODEL / GBN, T_SEQ / GBM);
    gemm_kernel<<<gsq, 256, 0, stream>>>(h, Wq, nullptr, nullptr, Qb, T_SEQ, D_MODEL, D_MODEL);
    gemm_kernel<<<gsq, 256, 0, stream>>>(h, Wk, nullptr, nullptr, Kb, T_SEQ, D_MODEL, D_MODEL);
    gemm_kernel<<<gsq, 256, 0, stream>>>(h, Wv, nullptr, nullptr, Vb, T_SEQ, D_MODEL, D_MODEL);

    // 5. ctx = causal_attention(Q,K,V)  (ctx reuses h buffer)
    float* ctx = h;
    dim3 gatt(T_SEQ / AQ, N_HEADS);
    attn_kernel<<<gatt, 256, 0, stream>>>(Qb, Kb, Vb, ctx);

    // 6. x2 = ctx @ Wo + bo + x
    gemm_kernel<<<gsq, 256, 0, stream>>>(ctx, Wo, bo, x, x2, T_SEQ, D_MODEL, D_MODEL);

    // 7. h2 = LN(x2; g2, s2)
    ln_kernel<<<T_SEQ, 256, 0, stream>>>(x2, g2, s2, h2);

    // 8-9. a = h2 @ w1 + b1 ; g = h2 @ w2 + b2
    dim3 gsf(FF_DIM / GBN, T_SEQ / GBM);
    gemm_kernel<<<gsf, 256, 0, stream>>>(h2, w1, b1, nullptr, abuf, T_SEQ, FF_DIM, D_MODEL);
    gemm_kernel<<<gsf, 256, 0, stream>>>(h2, w2, b2, nullptr, gbuf, T_SEQ, FF_DIM, D_MODEL);

    // 10. u = silu(a) * g  (in-place into abuf)
    const int n4 = (int)(TF / 4);
    swiglu_kernel<<<n4 / 256, 256, 0, stream>>>(abuf, gbuf, abuf, n4);

    // 11. out = u @ w3 + b3 + x2
    dim3 gso(D_MODEL / GBN, T_SEQ / GBM);
    gemm_kernel<<<gso, 256, 0, stream>>>(abuf, w3, b3, x2, out, T_SEQ, D_MODEL, FF_DIM);
}

// Round 2
// 2086.856 us; speedup vs baseline: 1.7688x; 1.7688x over previous
//
#include <hip/hip_runtime.h>
#include <hip/hip_bf16.h>

#define T_SEQ 4096
#define D_MODEL 768
#define N_HEADS 12
#define HEAD_DIM 64
#define FF_DIM 3072

// ---------------------------------------------------------------------------
// LayerNorm: one 256-thread block per row (D=768 -> 3 elements/thread)
// ---------------------------------------------------------------------------
__global__ __launch_bounds__(256) void ln_kernel(const float* __restrict__ x,
                                                 const float* __restrict__ g,
                                                 const float* __restrict__ b,
                                                 float* __restrict__ o) {
    const int row = blockIdx.x;
    const float* xr = x + (size_t)row * D_MODEL;
    float* orow = o + (size_t)row * D_MODEL;
    const int tid = threadIdx.x;

    float v0 = xr[tid];
    float v1 = xr[tid + 256];
    float v2 = xr[tid + 512];
    float sum = v0 + v1 + v2;

    __shared__ float red[4];
    __shared__ float mv[2];
    const int lane = tid & 63, wv = tid >> 6;

    #pragma unroll
    for (int off = 32; off > 0; off >>= 1) sum += __shfl_down(sum, off, 64);
    if (lane == 0) red[wv] = sum;
    __syncthreads();
    if (tid == 0) mv[0] = (red[0] + red[1] + red[2] + red[3]) * (1.0f / D_MODEL);
    __syncthreads();
    const float mean = mv[0];

    float d0 = v0 - mean, d1 = v1 - mean, d2 = v2 - mean;
    float sq = d0 * d0 + d1 * d1 + d2 * d2;
    #pragma unroll
    for (int off = 32; off > 0; off >>= 1) sq += __shfl_down(sq, off, 64);
    if (lane == 0) red[wv] = sq;
    __syncthreads();
    if (tid == 0) mv[1] = (red[0] + red[1] + red[2] + red[3]) * (1.0f / D_MODEL);
    __syncthreads();
    const float rs = rsqrtf(mv[1] + 1e-5f);

    orow[tid]       = g[tid]       * d0 * rs + b[tid];
    orow[tid + 256] = g[tid + 256] * d1 * rs + b[tid + 256];
    orow[tid + 512] = g[tid + 512] * d2 * rs + b[tid + 512];
}

// ---------------------------------------------------------------------------
// fp32 tiled GEMM: C[M,N] = A[M,K] @ B[K,N] (+ bias[N]) (+ res[M,N])
// BM=BN=64, BK=16, 256 threads, 4x4 micro-tile per thread.
// ---------------------------------------------------------------------------
#define GBM 64
#define GBN 64
#define GBK 16
#define GPAD 4

__global__ __launch_bounds__(256) void gemm_kernel(const float* __restrict__ A,
                                                   const float* __restrict__ B,
                                                   const float* __restrict__ bias,
                                                   const float* __restrict__ res,
                                                   float* __restrict__ C,
                                                   int M, int N, int K) {
    __shared__ float As[GBK][GBM + GPAD];
    __shared__ float Bs[GBK][GBN + GPAD];

    const int tid = threadIdx.x;
    const int bn = blockIdx.x * GBN;
    const int bm = blockIdx.y * GBM;
    const int tx = tid & 15;
    const int ty = tid >> 4;

    const int ar = tid >> 2;
    const int ac = (tid & 3) * 4;
    const int br = tid >> 4;
    const int bc = (tid & 15) * 4;

    float acc[4][4] = {};

    for (int k0 = 0; k0 < K; k0 += GBK) {
        float4 av = *(const float4*)(A + (size_t)(bm + ar) * K + k0 + ac);
        As[ac + 0][ar] = av.x;
        As[ac + 1][ar] = av.y;
        As[ac + 2][ar] = av.z;
        As[ac + 3][ar] = av.w;
        float4 bv = *(const float4*)(B + (size_t)(k0 + br) * N + bn + bc);
        *(float4*)(&Bs[br][bc]) = bv;
        __syncthreads();

        #pragma unroll
        for (int kk = 0; kk < GBK; ++kk) {
            float4 a = *(const float4*)(&As[kk][ty * 4]);
            float4 b = *(const float4*)(&Bs[kk][tx * 4]);
            acc[0][0] += a.x * b.x; acc[0][1] += a.x * b.y; acc[0][2] += a.x * b.z; acc[0][3] += a.x * b.w;
            acc[1][0] += a.y * b.x; acc[1][1] += a.y * b.y; acc[1][2] += a.y * b.z; acc[1][3] += a.y * b.w;
            acc[2][0] += a.z * b.x; acc[2][1] += a.z * b.y; acc[2][2] += a.z * b.z; acc[2][3] += a.z * b.w;
            acc[3][0] += a.w * b.x; acc[3][1] += a.w * b.y; acc[3][2] += a.w * b.z; acc[3][3] += a.w * b.w;
        }
        __syncthreads();
    }

    const int n0 = bn + tx * 4;
    float4 bias4 = make_float4(0.f, 0.f, 0.f, 0.f);
    if (bias) bias4 = *(const float4*)(bias + n0);

    #pragma unroll
    for (int i = 0; i < 4; ++i) {
        const int m = bm + ty * 4 + i;
        float4 out;
        out.x = acc[i][0] + bias4.x;
        out.y = acc[i][1] + bias4.y;
        out.z = acc[i][2] + bias4.z;
        out.w = acc[i][3] + bias4.w;
        if (res) {
            float4 r = *(const float4*)(res + (size_t)m * N + n0);
            out.x += r.x; out.y += r.y; out.z += r.z; out.w += r.w;
        }
        *(float4*)(C + (size_t)m * N + n0) = out;
    }
}

// ---------------------------------------------------------------------------
// Flash attention v2 (fp32, register micro-tiled).
// One block = (head, 64-query tile). 256 threads, 4x4 micro-tile per thread.
// LDS: Qt[d][qi] (Q transposed), KP = Kt[d][kj] during S-GEMM then Ps[kj][qi]
// during PV-GEMM (buffer reuse), Vs[kj][d]. Online softmax in registers with
// 16-lane shuffle reductions; O accumulator in registers.
// ---------------------------------------------------------------------------
#define APITCH 68

__global__ __launch_bounds__(256) void attn_kernel(const float* __restrict__ Q,
                                                   const float* __restrict__ K,
                                                   const float* __restrict__ V,
                                                   float* __restrict__ O) {
    const int h  = blockIdx.y;
    const int qt = (int)gridDim.x - 1 - (int)blockIdx.x;   // longest blocks first
    const int q0 = qt * 64;
    const int tid = threadIdx.x;
    const int tx = tid & 15;
    const int ty = tid >> 4;

    __shared__ float Qt[64][APITCH];
    __shared__ float KP[64][APITCH];
    __shared__ float Vs[64][APITCH];
    __shared__ float mrow[64];
    __shared__ float lrow[64];

    // load Q tile transposed: Qt[d][qi]
    {
        const int qi = tid >> 2;
        const int c0 = (tid & 3) * 16;
        const float* qrow = Q + (size_t)(q0 + qi) * D_MODEL + h * HEAD_DIM;
        #pragma unroll
        for (int cc = 0; cc < 16; cc += 4) {
            float4 v = *(const float4*)(qrow + c0 + cc);
            Qt[c0 + cc + 0][qi] = v.x;
            Qt[c0 + cc + 1][qi] = v.y;
            Qt[c0 + cc + 2][qi] = v.z;
            Qt[c0 + cc + 3][qi] = v.w;
        }
    }
    if (tid < 64) { mrow[tid] = -1e30f; lrow[tid] = 0.0f; }

    float o[4][4] = {};

    for (int kt = 0; kt <= qt; ++kt) {
        const int k0 = kt * 64;
        __syncthreads();  // previous-iteration KP/Vs reads complete (and init)

        // load K transposed -> KP, V natural -> Vs
        {
            const int kj = tid >> 2;
            const int c0 = (tid & 3) * 16;
            const float* krow = K + (size_t)(k0 + kj) * D_MODEL + h * HEAD_DIM;
            const float* vrow = V + (size_t)(k0 + kj) * D_MODEL + h * HEAD_DIM;
            #pragma unroll
            for (int cc = 0; cc < 16; cc += 4) {
                float4 kv = *(const float4*)(krow + c0 + cc);
                KP[c0 + cc + 0][kj] = kv.x;
                KP[c0 + cc + 1][kj] = kv.y;
                KP[c0 + cc + 2][kj] = kv.z;
                KP[c0 + cc + 3][kj] = kv.w;
                float4 vv = *(const float4*)(vrow + c0 + cc);
                *(float4*)(&Vs[kj][c0 + cc]) = vv;
            }
        }
        __syncthreads();  // tiles ready

        // S = Q @ K^T  (micro-tile GEMM over d)
        float s[4][4] = {};
        #pragma unroll 16
        for (int kk = 0; kk < 64; ++kk) {
            float4 a = *(const float4*)(&Qt[kk][ty * 4]);
            float4 b = *(const float4*)(&KP[kk][tx * 4]);
            s[0][0] += a.x * b.x; s[0][1] += a.x * b.y; s[0][2] += a.x * b.z; s[0][3] += a.x * b.w;
            s[1][0] += a.y * b.x; s[1][1] += a.y * b.y; s[1][2] += a.y * b.z; s[1][3] += a.y * b.w;
            s[2][0] += a.z * b.x; s[2][1] += a.z * b.y; s[2][2] += a.z * b.z; s[2][3] += a.z * b.w;
            s[3][0] += a.w * b.x; s[3][1] += a.w * b.y; s[3][2] += a.w * b.z; s[3][3] += a.w * b.w;
        }

        // mask + scale + online softmax (rows ty*4+i, all 16 tx lanes cooperate)
        float ps[4][4];
        float alpha[4];
        #pragma unroll
        for (int i = 0; i < 4; ++i) {
            const int grow = q0 + ty * 4 + i;
            float mx = -1e30f;
            #pragma unroll
            for (int j = 0; j < 4; ++j) {
                float sv = s[i][j] * 0.125f;           // 1/sqrt(64)
                if (k0 + tx * 4 + j > grow) sv = -1e30f;
                s[i][j] = sv;
                mx = fmaxf(mx, sv);
            }
            #pragma unroll
            for (int off = 1; off < 16; off <<= 1)
                mx = fmaxf(mx, __shfl_xor(mx, off, 64));
            const float mold = mrow[ty * 4 + i];       // same-wave lockstep read
            const float mnew = fmaxf(mold, mx);
            float sum = 0.0f;
            #pragma unroll
            for (int j = 0; j < 4; ++j) {
                float p = __expf(s[i][j] - mnew);
                ps[i][j] = p;
                sum += p;
            }
            #pragma unroll
            for (int off = 1; off < 16; off <<= 1)
                sum += __shfl_xor(sum, off, 64);
            alpha[i] = __expf(mold - mnew);
            if (tx == 0) {
                mrow[ty * 4 + i] = mnew;
                lrow[ty * 4 + i] = lrow[ty * 4 + i] * alpha[i] + sum;
            }
        }
        __syncthreads();  // S-GEMM reads of KP complete

        // write P into KP as Ps[kj][qi]; rescale O accumulator
        #pragma unroll
        for (int i = 0; i < 4; ++i) {
            #pragma unroll
            for (int j = 0; j < 4; ++j) {
                KP[tx * 4 + j][ty * 4 + i] = ps[i][j];
                o[i][j] *= alpha[i];
            }
        }
        __syncthreads();  // P ready

        // O += P @ V  (micro-tile GEMM over kj)
        #pragma unroll 16
        for (int kk = 0; kk < 64; ++kk) {
            float4 a = *(const float4*)(&KP[kk][ty * 4]);
            float4 b = *(const float4*)(&Vs[kk][tx * 4]);
            o[0][0] += a.x * b.x; o[0][1] += a.x * b.y; o[0][2] += a.x * b.z; o[0][3] += a.x * b.w;
            o[1][0] += a.y * b.x; o[1][1] += a.y * b.y; o[1][2] += a.y * b.z; o[1][3] += a.y * b.w;
            o[2][0] += a.z * b.x; o[2][1] += a.z * b.y; o[2][2] += a.z * b.z; o[2][3] += a.z * b.w;
            o[3][0] += a.w * b.x; o[3][1] += a.w * b.y; o[3][2] += a.w * b.z; o[3][3] += a.w * b.w;
        }
    }

    // epilogue: divide by l, store
    #pragma unroll
    for (int i = 0; i < 4; ++i) {
        const float inv = 1.0f / lrow[ty * 4 + i];
        float4 ov = make_float4(o[i][0] * inv, o[i][1] * inv, o[i][2] * inv, o[i][3] * inv);
        *(float4*)(O + (size_t)(q0 + ty * 4 + i) * D_MODEL + h * HEAD_DIM + tx * 4) = ov;
    }
}

// ---------------------------------------------------------------------------
// SwiGLU elementwise: o = silu(a) * g
// ---------------------------------------------------------------------------
__global__ __launch_bounds__(256) void swiglu_kernel(const float* __restrict__ a,
                                                     const float* __restrict__ g,
                                                     float* __restrict__ o,
                                                     int n4) {
    const int i = blockIdx.x * 256 + threadIdx.x;
    if (i < n4) {
        float4 av = ((const float4*)a)[i];
        float4 gv = ((const float4*)g)[i];
        float4 ov;
        ov.x = av.x / (1.0f + __expf(-av.x)) * gv.x;
        ov.y = av.y / (1.0f + __expf(-av.y)) * gv.y;
        ov.z = av.z / (1.0f + __expf(-av.z)) * gv.z;
        ov.w = av.w / (1.0f + __expf(-av.w)) * gv.w;
        ((float4*)o)[i] = ov;
    }
}

// ---------------------------------------------------------------------------
// launch
// ---------------------------------------------------------------------------
extern "C" void kernel_launch(void* const* d_in, const int* in_sizes, int n_in,
                              void* d_out, int out_size, void* d_ws, size_t ws_size,
                              hipStream_t stream) {
    const float* x  = (const float*)d_in[0];
    const float* Wq = (const float*)d_in[1];
    const float* Wk = (const float*)d_in[2];
    const float* Wv = (const float*)d_in[3];
    const float* Wo = (const float*)d_in[4];
    const float* bo = (const float*)d_in[5];
    const float* w1 = (const float*)d_in[6];
    const float* b1 = (const float*)d_in[7];
    const float* w2 = (const float*)d_in[8];
    const float* b2 = (const float*)d_in[9];
    const float* w3 = (const float*)d_in[10];
    const float* b3 = (const float*)d_in[11];
    const float* g1 = (const float*)d_in[12];
    const float* s1 = (const float*)d_in[13];
    const float* g2 = (const float*)d_in[14];
    const float* s2 = (const float*)d_in[15];
    float* out = (float*)d_out;

    const size_t TD = (size_t)T_SEQ * D_MODEL;
    const size_t TF = (size_t)T_SEQ * FF_DIM;

    float* ws = (float*)d_ws;
    float* h    = ws;            // TD (reused as ctx after QKV)
    float* Qb   = h    + TD;
    float* Kb   = Qb   + TD;
    float* Vb   = Kb   + TD;
    float* x2   = Vb   + TD;
    float* h2   = x2   + TD;
    float* abuf = h2   + TD;     // TF
    float* gbuf = abuf + TF;     // TF

    ln_kernel<<<T_SEQ, 256, 0, stream>>>(x, g1, s1, h);

    dim3 gsq(D_MODEL / GBN, T_SEQ / GBM);
    gemm_kernel<<<gsq, 256, 0, stream>>>(h, Wq, nullptr, nullptr, Qb, T_SEQ, D_MODEL, D_MODEL);
    gemm_kernel<<<gsq, 256, 0, stream>>>(h, Wk, nullptr, nullptr, Kb, T_SEQ, D_MODEL, D_MODEL);
    gemm_kernel<<<gsq, 256, 0, stream>>>(h, Wv, nullptr, nullptr, Vb, T_SEQ, D_MODEL, D_MODEL);

    float* ctx = h;
    dim3 gatt(T_SEQ / 64, N_HEADS);
    attn_kernel<<<gatt, 256, 0, stream>>>(Qb, Kb, Vb, ctx);

    gemm_kernel<<<gsq, 256, 0, stream>>>(ctx, Wo, bo, x, x2, T_SEQ, D_MODEL, D_MODEL);

    ln_kernel<<<T_SEQ, 256, 0, stream>>>(x2, g2, s2, h2);

    dim3 gsf(FF_DIM / GBN, T_SEQ / GBM);
    gemm_kernel<<<gsf, 256, 0, stream>>>(h2, w1, b1, nullptr, abuf, T_SEQ, FF_DIM, D_MODEL);
    gemm_kernel<<<gsf, 256, 0, stream>>>(h2, w2, b2, nullptr, gbuf, T_SEQ, FF_DIM, D_MODEL);

    const int n4 = (int)(TF / 4);
    swiglu_kernel<<<n4 / 256, 256, 0, stream>>>(abuf, gbuf, abuf, n4);

    dim3 gso(D_MODEL / GBN, T_SEQ / GBM);
    gemm_kernel<<<gso, 256, 0, stream>>>(abuf, w3, b3, x2, out, T_SEQ, D_MODEL, FF_DIM);
}

// Round 3
// 660.488 us; speedup vs baseline: 5.5887x; 3.1596x over previous
//
#include <hip/hip_runtime.h>

#define T_SEQ 4096
#define D_MODEL 768
#define N_HEADS 12
#define HEAD_DIM 64
#define FF_DIM 3072
#define QKV_LD 2304   // 3*D_MODEL
#define AG_LD  6144   // 2*FF_DIM

typedef __bf16 bf16x8 __attribute__((ext_vector_type(8)));
typedef float  f32x4  __attribute__((ext_vector_type(4)));

__device__ __forceinline__ unsigned short f2bf(float f) {
    unsigned int u = __float_as_uint(f);
    u += 0x7FFFu + ((u >> 16) & 1u);
    return (unsigned short)(u >> 16);
}
__device__ __forceinline__ float bf2f(unsigned short s) {
    return __uint_as_float(((unsigned int)s) << 16);
}
__device__ __forceinline__ f32x4 mfma16(bf16x8 a, bf16x8 b, f32x4 c) {
    return __builtin_amdgcn_mfma_f32_16x16x32_bf16(a, b, c, 0, 0, 0);
}

// ---------------------------------------------------------------------------
// Weight transpose + fp32->bf16: Wt[row_off+n][k] = bf16(W[k][n])
// grid (N/32, K/32), 256 threads
// ---------------------------------------------------------------------------
__global__ __launch_bounds__(256) void transpose_bf16(const float* __restrict__ W,
                                                      unsigned short* __restrict__ Wt,
                                                      int K, int N, int row_off) {
    __shared__ float tile[32][33];
    const int tx = threadIdx.x & 31, ty = threadIdx.x >> 5;  // 32 x 8
    const int n0 = blockIdx.x * 32, k0 = blockIdx.y * 32;
    #pragma unroll
    for (int s = 0; s < 32; s += 8)
        tile[ty + s][tx] = W[(size_t)(k0 + ty + s) * N + n0 + tx];
    __syncthreads();
    #pragma unroll
    for (int s = 0; s < 32; s += 8)
        Wt[(size_t)(row_off + n0 + ty + s) * K + k0 + tx] = f2bf(tile[tx][ty + s]);
}

// concat two fp32 vectors of length n into o[2n]
__global__ __launch_bounds__(256) void pack2_kernel(const float* __restrict__ a,
                                                    const float* __restrict__ b,
                                                    float* __restrict__ o, int n) {
    const int i = blockIdx.x * 256 + threadIdx.x;
    if (i < 2 * n) o[i] = (i < n) ? a[i] : b[i - n];
}

// ---------------------------------------------------------------------------
// LayerNorm (fp32 in, bf16 out): one 256-thread block per row
// ---------------------------------------------------------------------------
__global__ __launch_bounds__(256) void ln_kernel(const float* __restrict__ x,
                                                 const float* __restrict__ g,
                                                 const float* __restrict__ b,
                                                 unsigned short* __restrict__ o) {
    const int row = blockIdx.x;
    const float* xr = x + (size_t)row * D_MODEL;
    unsigned short* orow = o + (size_t)row * D_MODEL;
    const int tid = threadIdx.x;

    float v0 = xr[tid], v1 = xr[tid + 256], v2 = xr[tid + 512];
    float sum = v0 + v1 + v2;

    __shared__ float red[4];
    __shared__ float mv[2];
    const int lane = tid & 63, wv = tid >> 6;

    #pragma unroll
    for (int off = 32; off > 0; off >>= 1) sum += __shfl_down(sum, off, 64);
    if (lane == 0) red[wv] = sum;
    __syncthreads();
    if (tid == 0) mv[0] = (red[0] + red[1] + red[2] + red[3]) * (1.0f / D_MODEL);
    __syncthreads();
    const float mean = mv[0];

    float d0 = v0 - mean, d1 = v1 - mean, d2 = v2 - mean;
    float sq = d0 * d0 + d1 * d1 + d2 * d2;
    #pragma unroll
    for (int off = 32; off > 0; off >>= 1) sq += __shfl_down(sq, off, 64);
    if (lane == 0) red[wv] = sq;
    __syncthreads();
    if (tid == 0) mv[1] = (red[0] + red[1] + red[2] + red[3]) * (1.0f / D_MODEL);
    __syncthreads();
    const float rs = rsqrtf(mv[1] + 1e-5f);

    orow[tid]       = f2bf(g[tid]       * d0 * rs + b[tid]);
    orow[tid + 256] = f2bf(g[tid + 256] * d1 * rs + b[tid + 256]);
    orow[tid + 512] = f2bf(g[tid + 512] * d2 * rs + b[tid + 512]);
}

// ---------------------------------------------------------------------------
// bf16 MFMA GEMM: C[M,N] = A[M,K](bf16) @ Bt[N,K]^T(bf16) (+bias)(+res fp32)
// 128x128 tile, BK=32, 256 thr = 4 waves (2x2 of 64x64), 16x16x32 MFMA.
// LDS in fragment-chunk order: chunk(g, kq, r) -> 16B = X[g*16+r][kq*8..+8]
// Fragment read for wave: ds_read_b128 at ((g*64)+lane)*16  (sequential).
// ---------------------------------------------------------------------------
__global__ __launch_bounds__(256) void mfma_gemm(const unsigned short* __restrict__ A,
                                                 const unsigned short* __restrict__ Bt,
                                                 const float* __restrict__ bias,
                                                 const float* __restrict__ res,
                                                 float* __restrict__ Cf,
                                                 unsigned short* __restrict__ Cb,
                                                 int M, int N, int K) {
    __shared__ unsigned short Asm[128 * 32];
    __shared__ unsigned short Bsm[128 * 32];

    const int t = threadIdx.x;
    const int bn = blockIdx.x * 128;
    const int bm = blockIdx.y * 128;
    const int w = t >> 6, lane = t & 63;
    const int wy = w >> 1, wx = w & 1;

    f32x4 acc[4][4];
    const f32x4 fz = {0.f, 0.f, 0.f, 0.f};
    #pragma unroll
    for (int i = 0; i < 4; ++i)
        #pragma unroll
        for (int j = 0; j < 4; ++j) acc[i][j] = fz;

    for (int k0 = 0; k0 < K; k0 += 32) {
        #pragma unroll
        for (int s = 0; s < 2; ++s) {
            const int c = t + s * 256;                 // 0..511
            const int kq = c & 3, rr = (c >> 2) & 15, gg = c >> 6;
            const int row = gg * 16 + rr;
            const int lc = (gg * 64 + kq * 16 + rr) * 8;
            uint4 va = *(const uint4*)(A + (size_t)(bm + row) * K + k0 + kq * 8);
            *(uint4*)(Asm + lc) = va;
            uint4 vb = *(const uint4*)(Bt + (size_t)(bn + row) * K + k0 + kq * 8);
            *(uint4*)(Bsm + lc) = vb;
        }
        __syncthreads();

        bf16x8 af[4], bf[4];
        #pragma unroll
        for (int mi = 0; mi < 4; ++mi)
            af[mi] = *(const bf16x8*)(Asm + ((wy * 4 + mi) * 64 + lane) * 8);
        #pragma unroll
        for (int ni = 0; ni < 4; ++ni)
            bf[ni] = *(const bf16x8*)(Bsm + ((wx * 4 + ni) * 64 + lane) * 8);
        #pragma unroll
        for (int mi = 0; mi < 4; ++mi)
            #pragma unroll
            for (int ni = 0; ni < 4; ++ni)
                acc[mi][ni] = mfma16(af[mi], bf[ni], acc[mi][ni]);
        __syncthreads();
    }

    const int quad = lane >> 4, r = lane & 15;
    float bv[4];
    #pragma unroll
    for (int ni = 0; ni < 4; ++ni)
        bv[ni] = bias ? bias[bn + wx * 64 + ni * 16 + r] : 0.0f;

    #pragma unroll
    for (int mi = 0; mi < 4; ++mi) {
        #pragma unroll
        for (int i = 0; i < 4; ++i) {
            const int m = bm + wy * 64 + mi * 16 + quad * 4 + i;
            #pragma unroll
            for (int ni = 0; ni < 4; ++ni) {
                const int n = bn + wx * 64 + ni * 16 + r;
                float v = acc[mi][ni][i] + bv[ni];
                if (res) v += res[(size_t)m * N + n];
                if (Cf) Cf[(size_t)m * N + n] = v;
                else    Cb[(size_t)m * N + n] = f2bf(v);
            }
        }
    }
}

// ---------------------------------------------------------------------------
// Flash attention, bf16 MFMA. Block = (64 q-rows, head); wave = 16 q-rows.
// qkv: [T][2304] bf16 (Q|K|V); ctx out: [T][768] bf16.
// S = Q K^T via 16x16x32 MFMA (Q-frags in registers, K in LDS frag order);
// fp32 online softmax (row state in registers, 16-lane shuffle reduce);
// P -> bf16 -> per-wave LDS (A-frag order); V transposed in LDS (B-frag order).
// ---------------------------------------------------------------------------
__global__ __launch_bounds__(256) void attn_mfma(const unsigned short* __restrict__ qkv,
                                                 unsigned short* __restrict__ ctx) {
    const int h = blockIdx.y;
    const int qt = (int)gridDim.x - 1 - (int)blockIdx.x;   // longest-first
    const int q0 = qt * 64;
    const int t = threadIdx.x;
    const int w = t >> 6, lane = t & 63;
    const int quad = lane >> 4, r = lane & 15;

    __shared__ unsigned short Ks[512 * 8];      // 8 KB  (chunk order)
    __shared__ unsigned short Vs[512 * 8];      // 8 KB  (transposed, chunk order)
    __shared__ unsigned short Ps[4][128 * 8];   // 2 KB per wave (A-frag order)

    // Q fragments for this wave's 16 rows, held for the whole block
    bf16x8 aq[2];
    {
        const unsigned short* qp = qkv + (size_t)(q0 + w * 16 + r) * QKV_LD + h * 64 + quad * 8;
        aq[0] = *(const bf16x8*)(qp);
        aq[1] = *(const bf16x8*)(qp + 32);
    }

    const f32x4 fz = {0.f, 0.f, 0.f, 0.f};
    f32x4 acc_o[4] = {fz, fz, fz, fz};
    float mrow[4] = {-1e30f, -1e30f, -1e30f, -1e30f};
    float lrow[4] = {0.f, 0.f, 0.f, 0.f};

    for (int kt = 0; kt <= qt; ++kt) {
        const int k0 = kt * 64;

        // stage K tile (chunk order): c -> ks=(c>>2)&1, kq=c&3, key=c>>3
        #pragma unroll
        for (int s = 0; s < 2; ++s) {
            const int c = t + s * 256;
            const int ks_ = (c >> 2) & 1, kq_ = c & 3, key = c >> 3;
            uint4 v = *(const uint4*)(qkv + (size_t)(k0 + key) * QKV_LD + D_MODEL + h * 64 + ks_ * 32 + kq_ * 8);
            const int lc = ((ks_ * 4 + (key >> 4)) * 64 + kq_ * 16 + (key & 15)) * 8;
            *(uint4*)(Ks + lc) = v;
        }
        // stage V transposed: element (key,d) -> chunk(ks=key>>5, ni=d>>4, kq=(key>>3)&3, r=d&15), j=key&7
        #pragma unroll
        for (int s = 0; s < 2; ++s) {
            const int key = (t >> 3) + s * 32;
            const int d0 = (t & 7) * 8;
            uint4 vv = *(const uint4*)(qkv + (size_t)(k0 + key) * QKV_LD + 2 * D_MODEL + h * 64 + d0);
            const unsigned short* pv = (const unsigned short*)&vv;
            const int ksv = key >> 5, kqv = (key >> 3) & 3, jj = key & 7;
            #pragma unroll
            for (int j = 0; j < 8; ++j) {
                const int d = d0 + j;
                Vs[((ksv * 4 + (d >> 4)) * 64 + kqv * 16 + (d & 15)) * 8 + jj] = pv[j];
            }
        }
        __syncthreads();

        // S = Q @ K^T
        f32x4 sacc[4] = {fz, fz, fz, fz};
        #pragma unroll
        for (int ks = 0; ks < 2; ++ks)
            #pragma unroll
            for (int ni = 0; ni < 4; ++ni) {
                bf16x8 bk = *(const bf16x8*)(Ks + ((ks * 4 + ni) * 64 + lane) * 8);
                sacc[ni] = mfma16(aq[ks], bk, sacc[ni]);
            }

        // online softmax (rows quad*4+i of this wave's 16)
        const bool diag = (kt == qt);
        float alpha[4];
        #pragma unroll
        for (int i = 0; i < 4; ++i) {
            const int qg = q0 + w * 16 + quad * 4 + i;
            float sv[4];
            float mx = -1e30f;
            #pragma unroll
            for (int ni = 0; ni < 4; ++ni) {
                float xv = sacc[ni][i] * 0.125f;               // 1/sqrt(64)
                if (diag && (k0 + ni * 16 + r > qg)) xv = -1e30f;
                sv[ni] = xv;
                mx = fmaxf(mx, xv);
            }
            #pragma unroll
            for (int off = 1; off < 16; off <<= 1)
                mx = fmaxf(mx, __shfl_xor(mx, off, 64));
            const float mnew = fmaxf(mrow[i], mx);
            float sum = 0.f;
            unsigned short pb[4];
            #pragma unroll
            for (int ni = 0; ni < 4; ++ni) {
                float p = __expf(sv[ni] - mnew);
                sum += p;
                pb[ni] = f2bf(p);
            }
            #pragma unroll
            for (int off = 1; off < 16; off <<= 1)
                sum += __shfl_xor(sum, off, 64);
            alpha[i] = __expf(mrow[i] - mnew);
            mrow[i] = mnew;
            lrow[i] = lrow[i] * alpha[i] + sum;
            // write P (bf16) into this wave's region, A-frag order
            #pragma unroll
            for (int ni = 0; ni < 4; ++ni) {
                const int key = ni * 16 + r;
                Ps[w][((key >> 5) * 64 + ((key >> 3) & 3) * 16 + (quad * 4 + i)) * 8 + (key & 7)] = pb[ni];
            }
            #pragma unroll
            for (int nd = 0; nd < 4; ++nd) acc_o[nd][i] *= alpha[i];
        }
        __syncthreads();   // P visible; S-phase K reads complete

        // O += P @ V
        #pragma unroll
        for (int ks = 0; ks < 2; ++ks) {
            bf16x8 ap = *(const bf16x8*)(&Ps[w][(ks * 64 + lane) * 8]);
            #pragma unroll
            for (int nd = 0; nd < 4; ++nd) {
                bf16x8 bv = *(const bf16x8*)(Vs + ((ks * 4 + nd) * 64 + lane) * 8);
                acc_o[nd] = mfma16(ap, bv, acc_o[nd]);
            }
        }
        __syncthreads();   // Vt/P reads complete before next staging
    }

    // epilogue
    #pragma unroll
    for (int i = 0; i < 4; ++i) {
        const float inv = 1.0f / lrow[i];
        const size_t rowo = (size_t)(q0 + w * 16 + quad * 4 + i) * D_MODEL + h * 64;
        #pragma unroll
        for (int nd = 0; nd < 4; ++nd)
            ctx[rowo + nd * 16 + r] = f2bf(acc_o[nd][i] * inv);
    }
}

// ---------------------------------------------------------------------------
// SwiGLU: u[t][c] = silu(ag[t][c]) * ag[t][c+3072]   (bf16 in/out)
// grid = T blocks of 384 threads (8 elems each)
// ---------------------------------------------------------------------------
__global__ __launch_bounds__(384) void swiglu_kernel(const unsigned short* __restrict__ ag,
                                                     unsigned short* __restrict__ u) {
    const int row = blockIdx.x;
    const int c8 = threadIdx.x;
    const size_t base = (size_t)row * AG_LD + (size_t)c8 * 8;
    uint4 a4 = *(const uint4*)(ag + base);
    uint4 g4 = *(const uint4*)(ag + base + FF_DIM);
    const unsigned short* ap = (const unsigned short*)&a4;
    const unsigned short* gp = (const unsigned short*)&g4;
    unsigned short ou[8];
    #pragma unroll
    for (int j = 0; j < 8; ++j) {
        float a = bf2f(ap[j]);
        float g = bf2f(gp[j]);
        ou[j] = f2bf(a / (1.0f + __expf(-a)) * g);
    }
    *(uint4*)(u + (size_t)row * FF_DIM + (size_t)c8 * 8) = *(uint4*)ou;
}

// ---------------------------------------------------------------------------
// launch
// ---------------------------------------------------------------------------
extern "C" void kernel_launch(void* const* d_in, const int* in_sizes, int n_in,
                              void* d_out, int out_size, void* d_ws, size_t ws_size,
                              hipStream_t stream) {
    const float* x  = (const float*)d_in[0];
    const float* Wq = (const float*)d_in[1];
    const float* Wk = (const float*)d_in[2];
    const float* Wv = (const float*)d_in[3];
    const float* Wo = (const float*)d_in[4];
    const float* bo = (const float*)d_in[5];
    const float* w1 = (const float*)d_in[6];
    const float* b1 = (const float*)d_in[7];
    const float* w2 = (const float*)d_in[8];
    const float* b2 = (const float*)d_in[9];
    const float* w3 = (const float*)d_in[10];
    const float* b3 = (const float*)d_in[11];
    const float* g1 = (const float*)d_in[12];
    const float* s1 = (const float*)d_in[13];
    const float* g2 = (const float*)d_in[14];
    const float* s2 = (const float*)d_in[15];
    float* out = (float*)d_out;

    const size_t TD = (size_t)T_SEQ * D_MODEL;

    char* p = (char*)d_ws;
    auto alloc = [&](size_t bytes) { char* r = p; p += (bytes + 255) & ~(size_t)255; return r; };
    unsigned short* h      = (unsigned short*)alloc(TD * 2);
    unsigned short* qkv    = (unsigned short*)alloc((size_t)T_SEQ * QKV_LD * 2);
    unsigned short* ctx    = (unsigned short*)alloc(TD * 2);
    float*          x2     = (float*)alloc(TD * 4);
    unsigned short* h2     = (unsigned short*)alloc(TD * 2);
    unsigned short* ag     = (unsigned short*)alloc((size_t)T_SEQ * AG_LD * 2);
    unsigned short* u      = (unsigned short*)alloc((size_t)T_SEQ * FF_DIM * 2);
    unsigned short* Wqkv_t = (unsigned short*)alloc((size_t)QKV_LD * D_MODEL * 2);
    unsigned short* Wo_t   = (unsigned short*)alloc((size_t)D_MODEL * D_MODEL * 2);
    unsigned short* W12_t  = (unsigned short*)alloc((size_t)AG_LD * D_MODEL * 2);
    unsigned short* W3_t   = (unsigned short*)alloc((size_t)D_MODEL * FF_DIM * 2);
    float*          b12    = (float*)alloc((size_t)AG_LD * 4);

    // --- weight prep (bf16 transposed) ---
    transpose_bf16<<<dim3(24, 24), 256, 0, stream>>>(Wq, Wqkv_t, D_MODEL, D_MODEL, 0);
    transpose_bf16<<<dim3(24, 24), 256, 0, stream>>>(Wk, Wqkv_t, D_MODEL, D_MODEL, D_MODEL);
    transpose_bf16<<<dim3(24, 24), 256, 0, stream>>>(Wv, Wqkv_t, D_MODEL, D_MODEL, 2 * D_MODEL);
    transpose_bf16<<<dim3(24, 24), 256, 0, stream>>>(Wo, Wo_t, D_MODEL, D_MODEL, 0);
    transpose_bf16<<<dim3(96, 24), 256, 0, stream>>>(w1, W12_t, D_MODEL, FF_DIM, 0);
    transpose_bf16<<<dim3(96, 24), 256, 0, stream>>>(w2, W12_t, D_MODEL, FF_DIM, FF_DIM);
    transpose_bf16<<<dim3(24, 96), 256, 0, stream>>>(w3, W3_t, FF_DIM, D_MODEL, 0);
    pack2_kernel<<<24, 256, 0, stream>>>(b1, b2, b12, FF_DIM);

    // --- block ---
    ln_kernel<<<T_SEQ, 256, 0, stream>>>(x, g1, s1, h);

    mfma_gemm<<<dim3(QKV_LD / 128, T_SEQ / 128), 256, 0, stream>>>(
        h, Wqkv_t, nullptr, nullptr, nullptr, qkv, T_SEQ, QKV_LD, D_MODEL);

    attn_mfma<<<dim3(T_SEQ / 64, N_HEADS), 256, 0, stream>>>(qkv, ctx);

    mfma_gemm<<<dim3(D_MODEL / 128, T_SEQ / 128), 256, 0, stream>>>(
        ctx, Wo_t, bo, x, x2, nullptr, T_SEQ, D_MODEL, D_MODEL);

    ln_kernel<<<T_SEQ, 256, 0, stream>>>(x2, g2, s2, h2);

    mfma_gemm<<<dim3(AG_LD / 128, T_SEQ / 128), 256, 0, stream>>>(
        h2, W12_t, b12, nullptr, nullptr, ag, T_SEQ, AG_LD, D_MODEL);

    swiglu_kernel<<<T_SEQ, 384, 0, stream>>>(ag, u);

    mfma_gemm<<<dim3(D_MODEL / 128, T_SEQ / 128), 256, 0, stream>>>(
        u, W3_t, b3, x2, out, nullptr, T_SEQ, D_MODEL, FF_DIM);
}